// Round 8
// baseline (456.388 us; speedup 1.0000x reference)
//
#include <hip/hip_runtime.h>

#define NORD 256
#define TLEN 4096
#define HTLEN 2048
#define NBATCH 512
#define NBLK 256
#define NTHR 256

// ---------------- two-level generation grid barrier (256 blocks, 16x16) ----------------
// bar[0]=gen, bar[32]=root counter, bar[64+32*grp]=group counters. All monotonic
// (no resets): barrier g completes when each counter reaches 16*(g+1).
// Spin is BOUNDED (~0.2s) so a lost block degrades to wrong-answer, never a GPU wedge.
__device__ __forceinline__ void gbar(int* bar) {
  __syncthreads();
  if (threadIdx.x == 0) {
    int* gen = bar;
    int* root = bar + 32;
    int* grpc = bar + 64 + ((blockIdx.x >> 4) << 5);
    const int g = __hip_atomic_load(gen, __ATOMIC_RELAXED, __HIP_MEMORY_SCOPE_AGENT);
    __threadfence();  // release: my phase's writes visible device-wide
    bool last = false;
    if (__hip_atomic_fetch_add(grpc, 1, __ATOMIC_ACQ_REL, __HIP_MEMORY_SCOPE_AGENT) ==
        (g << 4) + 15) {
      if (__hip_atomic_fetch_add(root, 1, __ATOMIC_ACQ_REL, __HIP_MEMORY_SCOPE_AGENT) ==
          (g << 4) + 15) {
        __hip_atomic_store(gen, g + 1, __ATOMIC_RELEASE, __HIP_MEMORY_SCOPE_AGENT);
        last = true;
      }
    }
    if (!last) {
      for (int spin = 0; spin < (1 << 22); ++spin) {
        if (__hip_atomic_load(gen, __ATOMIC_RELAXED, __HIP_MEMORY_SCOPE_AGENT) != g) break;
        __builtin_amdgcn_s_sleep(2);
      }
    }
    __threadfence();  // acquire: see other blocks' writes
  }
  __syncthreads();
}

// ---------------- k-major LDS tile helpers ([32][68], coalesced fills) ----------------
__device__ __forceinline__ void tile_fma4(const float (*As)[68], const float (*Bs)[68],
                                          int tr, int tc, float acc[4][4]) {
#pragma unroll
  for (int k = 0; k < 32; ++k) {
    const float4 a4 = *reinterpret_cast<const float4*>(&As[k][4 * tr]);
    const float4 b4 = *reinterpret_cast<const float4*>(&Bs[k][4 * tc]);
    const float a[4] = {a4.x, a4.y, a4.z, a4.w};
    const float b[4] = {b4.x, b4.y, b4.z, b4.w};
#pragma unroll
    for (int ii = 0; ii < 4; ++ii)
#pragma unroll
      for (int jj = 0; jj < 4; ++jj)
        acc[ii][jj] += a[ii] * b[jj];
  }
}

__device__ __forceinline__ void fill_tr(float (*dst)[68], const float* __restrict__ s0,
                                        const float* __restrict__ s1,
                                        int row0, int stride, int k0, int t) {
  const int rr = t >> 3, cc = (t & 7) << 2;
#pragma unroll
  for (int p = 0; p < 64; p += 32) {
    const size_t off = (size_t)(row0 + rr + p) * stride + k0 + cc;
    float4 v = *reinterpret_cast<const float4*>(s0 + off);
    if (s1) {
      const float4 w = *reinterpret_cast<const float4*>(s1 + off);
      v.x += w.x; v.y += w.y; v.z += w.z; v.w += w.w;
    }
    dst[cc + 0][rr + p] = v.x; dst[cc + 1][rr + p] = v.y;
    dst[cc + 2][rr + p] = v.z; dst[cc + 3][rr + p] = v.w;
  }
}

// phases: 0 inv+zeroing; 1..11 doubling round s=ph-1; 12 final GEMM; 13 combine.
__global__ __launch_bounds__(NTHR) void hippo_all(
    const float* __restrict__ A, const float* __restrict__ Bm,
    const float* __restrict__ f,
    float* P00, float* P01, float* P10, float* P11,
    float* U0, float* U1, float* Glow, float* C,
    int* bar, int ph_lo, int ph_hi, int use_bar) {
  const int bid = blockIdx.x;
  const int t = threadIdx.x;
  const int tr = t >> 4, tc = t & 15;

  __shared__ float xs[NORD];
  __shared__ float As[32][68];
  __shared__ float Bs0[32][68];
  __shared__ float Bs1[32][68];

  for (int ph = ph_lo; ph <= ph_hi; ++ph) {
    if (ph == 0) {
      // zero C, Glow (512 floats per block each), split parts
      {
        const int base = bid * 512;
        C[base + t] = 0.0f; C[base + 256 + t] = 0.0f;
        Glow[base + t] = 0.0f; Glow[base + 256 + t] = 0.0f;
        if (P01) P01[(size_t)bid * 256 + t] = 0.0f;
        if (U1 && bid == 0) U1[t] = 0.0f;
      }
      // triangular inverse: block bid solves column (255-bid); block 0 also solves Bd.
      const int ntask = (bid == 0) ? 2 : 1;
      for (int task = 0; task < ntask; ++task) {
        const int col = (task == 0) ? (NORD - 1 - bid) : -1;  // -1 => Bd
        const int i = t;
        const int wave = i >> 6, lane = i & 63;
        float b = (col >= 0) ? ((i == col) ? 1.0f : 0.0f) : Bm[i];
        const float invd = 1.0f / (1.0f - 0.5f * A[i * NORD + i]);
        for (int w = 0; w < 4; ++w) {
          if (wave == w) {
            const int base = w << 6;
            for (int jj = 0; jj < 64; ++jj) {
              float bj = __shfl(b, jj);
              float dj = __shfl(invd, jj);
              float xj = bj * dj;
              if (lane > jj) {
                b += 0.5f * A[i * NORD + base + jj] * xj;
              } else if (lane == jj) {
                b = xj;
              }
            }
            xs[i] = b;
          }
          __syncthreads();
          if (wave > w) {
            const int base = w << 6;
            const float4* arow = reinterpret_cast<const float4*>(A + i * NORD + base);
#pragma unroll
            for (int q = 0; q < 16; ++q) {
              float4 a4 = arow[q];
              b += 0.5f * (a4.x * xs[base + 4 * q + 0] + a4.y * xs[base + 4 * q + 1] +
                           a4.z * xs[base + 4 * q + 2] + a4.w * xs[base + 4 * q + 3]);
            }
          }
        }
        if (col >= 0) {
          P00[i * NORD + col] = 2.0f * b - ((i == col) ? 1.0f : 0.0f);
        } else {
          U0[i] = b;
        }
        __syncthreads();
      }
    } else if (ph <= 11) {
      const int s = ph - 1;
      const int J = 1 << s;
      const float* Pin0 = (s & 1) ? P10 : P00;
      const float* Pin1 = (s & 1) ? P11 : P01;
      float* Pout0 = (s & 1) ? P00 : P10;
      float* Pout1 = (s & 1) ? P01 : P11;
      const int KS = U1 ? 2 : 1;
      const int rtiles = (J + 63) >> 6;
      const int n_apply = (rtiles << 2) * KS;
      const int kspan = U1 ? 128 : 256;

      if (bid < n_apply) {
        int work = bid, ks = 0;
        if (U1) { ks = work & 1; work >>= 1; }
        const int j0 = (work >> 2) << 6;
        const int m0 = (work & 3) << 6;
        const int klo = ks * kspan;
        float acc[4][4] = {};
        for (int kc = 0; kc < kspan; kc += 32) {
          const int k0 = klo + kc;
          fill_tr(As, U0, U1, j0, NORD, k0, t);
          fill_tr(Bs0, Pin0, Pin1, m0, NORD, k0, t);
          __syncthreads();
          tile_fma4(As, Bs0, tr, tc, acc);
          __syncthreads();
        }
        float* Ud = ks ? U1 : U0;
#pragma unroll
        for (int ii = 0; ii < 4; ++ii) {
          const int lr = j0 + 4 * tr + ii;
          if (lr < J) {
            float4 v = {acc[ii][0], acc[ii][1], acc[ii][2], acc[ii][3]};
            *reinterpret_cast<float4*>(&Ud[(size_t)(J + lr) * NORD + m0 + 4 * tc]) = v;
          }
        }
      } else if (bid < n_apply + 16 * KS) {
        int q = bid - n_apply, ks = 0;
        if (Pin1) { ks = q & 1; q >>= 1; }
        const int m0s = (q >> 2) << 6;
        const int n0 = (q & 3) << 6;
        const int klo = ks * kspan;
        const int rr = t >> 3, cc = (t & 7) << 2;
        float acc[4][4] = {};
        for (int kc = 0; kc < kspan; kc += 32) {
          const int k0 = klo + kc;
          fill_tr(As, Pin0, Pin1, m0s, NORD, k0, t);
#pragma unroll
          for (int p = 0; p < 64; p += 32) {
            const size_t off = (size_t)(k0 + rr) * NORD + n0 + cc + p;
            float4 v = *reinterpret_cast<const float4*>(Pin0 + off);
            if (Pin1) {
              const float4 w = *reinterpret_cast<const float4*>(Pin1 + off);
              v.x += w.x; v.y += w.y; v.z += w.z; v.w += w.w;
            }
            *reinterpret_cast<float4*>(&Bs0[rr][cc + p]) = v;
          }
          __syncthreads();
          tile_fma4(As, Bs0, tr, tc, acc);
          __syncthreads();
        }
        float* Pd = ks ? Pout1 : Pout0;
#pragma unroll
        for (int ii = 0; ii < 4; ++ii) {
          float4 v = {acc[ii][0], acc[ii][1], acc[ii][2], acc[ii][3]};
          *reinterpret_cast<float4*>(&Pd[(size_t)(m0s + 4 * tr + ii) * NORD + n0 + 4 * tc]) = v;
        }
      }
    } else if (ph == 12) {
      // G[h*512+b][m] += sum_{j<2048} f[b][2048h+j]*Usum[2047-j][m]; splitK=8.
      const int tile = bid >> 3, ks = bid & 7;
      const int rt = tile >> 1, ct = tile & 1;
      const int h = rt >> 3;
      const int b0 = (rt & 7) << 6;
      const int m0 = ct << 7;
      const int jbase = ks << 8;
      const int rr = t >> 3, cc = (t & 7) << 2;
      const int jr = t >> 5, c32 = t & 31;
      float acc[4][8] = {};
      for (int kc = 0; kc < 256; kc += 32) {
        const int j0 = jbase + kc;
#pragma unroll
        for (int p = 0; p < 64; p += 32) {
          const float4 v = *reinterpret_cast<const float4*>(
              f + (size_t)(b0 + rr + p) * TLEN + HTLEN * h + j0 + cc);
          As[cc + 0][rr + p] = v.x; As[cc + 1][rr + p] = v.y;
          As[cc + 2][rr + p] = v.z; As[cc + 3][rr + p] = v.w;
        }
#pragma unroll
        for (int p = 0; p < 32; p += 8) {
          const int jj = jr + p;
          const size_t off = (size_t)(HTLEN - 1 - (j0 + jj)) * NORD + m0 + 4 * c32;
          float4 v = *reinterpret_cast<const float4*>(U0 + off);
          if (U1) {
            const float4 w = *reinterpret_cast<const float4*>(U1 + off);
            v.x += w.x; v.y += w.y; v.z += w.z; v.w += w.w;
          }
          if (c32 < 16) *reinterpret_cast<float4*>(&Bs0[jj][4 * c32]) = v;
          else          *reinterpret_cast<float4*>(&Bs1[jj][4 * (c32 - 16)]) = v;
        }
        __syncthreads();
#pragma unroll
        for (int k = 0; k < 32; ++k) {
          const float4 a4 = *reinterpret_cast<const float4*>(&As[k][4 * tr]);
          const float4 b4 = *reinterpret_cast<const float4*>(&Bs0[k][4 * tc]);
          const float4 b5 = *reinterpret_cast<const float4*>(&Bs1[k][4 * tc]);
          const float a[4] = {a4.x, a4.y, a4.z, a4.w};
          const float b[8] = {b4.x, b4.y, b4.z, b4.w, b5.x, b5.y, b5.z, b5.w};
#pragma unroll
          for (int ii = 0; ii < 4; ++ii)
#pragma unroll
            for (int jj = 0; jj < 8; ++jj)
              acc[ii][jj] += a[ii] * b[jj];
        }
        __syncthreads();
      }
      float* dst = h ? C : Glow;
#pragma unroll
      for (int ii = 0; ii < 4; ++ii) {
        const int row = b0 + 4 * tr + ii;
#pragma unroll
        for (int jj = 0; jj < 8; ++jj) {
          const int col = m0 + ((jj < 4) ? (4 * tc + jj) : (64 + 4 * tc + (jj - 4)));
          atomicAdd(dst + (size_t)row * NORD + col, acc[ii][jj]);
        }
      }
    } else if (bid < 32) {
      // combine: C[b][m] += sum_n Glow[b][n] * P2048[m][n]; P2048 = P10(+P11).
      const int b0 = (bid >> 2) << 6;
      const int m0 = (bid & 3) << 6;
      const int rr = t >> 3, cc = (t & 7) << 2;
      float acc[4][4] = {};
      for (int k0 = 0; k0 < NORD; k0 += 32) {
        // As[n][r] = Glow[b0+r][k0+n] via agent-scope atomic loads (cross-XCD safety)
#pragma unroll
        for (int p = 0; p < 64; p += 32) {
          const size_t off = (size_t)(b0 + rr + p) * NORD + k0 + cc;
#pragma unroll
          for (int q = 0; q < 4; ++q)
            As[cc + q][rr + p] =
                __hip_atomic_load(Glow + off + q, __ATOMIC_RELAXED, __HIP_MEMORY_SCOPE_AGENT);
        }
        fill_tr(Bs0, P10, P11, m0, NORD, k0, t);
        __syncthreads();
        tile_fma4(As, Bs0, tr, tc, acc);
        __syncthreads();
      }
#pragma unroll
      for (int ii = 0; ii < 4; ++ii)
#pragma unroll
        for (int jj = 0; jj < 4; ++jj) {
          float* p = C + (size_t)(b0 + 4 * tr + ii) * NORD + m0 + 4 * tc + jj;
          const float cur =
              __hip_atomic_load(p, __ATOMIC_RELAXED, __HIP_MEMORY_SCOPE_AGENT);
          *p = cur + acc[ii][jj];
        }
    }
    if (use_bar && ph < ph_hi) gbar(bar);
  }
}

// ---------------------------------------------------------------------------
extern "C" void kernel_launch(void* const* d_in, const int* in_sizes, int n_in,
                              void* d_out, int out_size, void* d_ws, size_t ws_size,
                              hipStream_t stream) {
  const float* f  = (const float*)d_in[0];   // (512, 4096)
  const float* A  = (const float*)d_in[1];   // (256, 256) lower triangular
  const float* Bm = (const float*)d_in[2];   // (256, 1)
  // d_in[3] = init_state == 0 -> no contribution.

  float* ws = (float*)d_ws;
  const size_t need_split =
      (size_t)(4 * 65536 + 2 * 524288 + 131072 + 1024) * sizeof(float);
  const int KS = (ws_size >= need_split) ? 2 : 1;

  float *P00, *P01, *P10, *P11, *U0, *U1, *Glow;
  int* bar;
  if (KS == 2) {
    P00 = ws;            P01 = ws + 65536;
    P10 = ws + 131072;   P11 = ws + 196608;
    U0  = ws + 262144;   U1  = ws + 786432;
    Glow = ws + 1310720;
    bar = (int*)(ws + 1441792);
  } else {
    P00 = ws;            P01 = nullptr;
    P10 = ws + 65536;    P11 = nullptr;
    U0  = ws + 131072;   U1  = nullptr;
    Glow = ws + 655360;
    bar = (int*)(ws + 786432);
  }
  float* C = (float*)d_out;

  hipMemsetAsync(bar, 0, 576 * sizeof(int), stream);

  int pl = 0, phh = 13, ub = 1;
  void* args[] = {(void*)&A, (void*)&Bm, (void*)&f,
                  (void*)&P00, (void*)&P01, (void*)&P10, (void*)&P11,
                  (void*)&U0, (void*)&U1, (void*)&Glow, (void*)&C,
                  (void*)&bar, (void*)&pl, (void*)&phh, (void*)&ub};
  hipError_t e = hipLaunchCooperativeKernel((void*)hippo_all, dim3(NBLK), dim3(NTHR),
                                            args, 0, stream);
  if (e != hipSuccess) {
    // fallback: one launch per phase (launch boundary = grid sync)
    for (int p = 0; p <= 13; ++p) {
      hipLaunchKernelGGL(hippo_all, dim3(NBLK), dim3(NTHR), 0, stream,
                         A, Bm, f, P00, P01, P10, P11, U0, U1, Glow, C,
                         bar, p, p, 0);
    }
  }
}

// Round 9
// 246.397 us; speedup vs baseline: 1.8522x; 1.8522x over previous
//
#include <hip/hip_runtime.h>

#define NORD 256
#define TLEN 4096
#define NBATCH 512

// ---------------- k-major LDS tile helpers ([32][68], coalesced fills) ----------------
__device__ __forceinline__ void tile_fma4(const float (*As)[68], const float (*Bs)[68],
                                          int tr, int tc, float acc[4][4]) {
#pragma unroll
  for (int k = 0; k < 32; ++k) {
    const float4 a4 = *reinterpret_cast<const float4*>(&As[k][4 * tr]);
    const float4 b4 = *reinterpret_cast<const float4*>(&Bs[k][4 * tc]);
    const float a[4] = {a4.x, a4.y, a4.z, a4.w};
    const float b[4] = {b4.x, b4.y, b4.z, b4.w};
#pragma unroll
    for (int ii = 0; ii < 4; ++ii)
#pragma unroll
      for (int jj = 0; jj < 4; ++jj)
        acc[ii][jj] += a[ii] * b[jj];
  }
}

__device__ __forceinline__ void fill_tr(float (*dst)[68], const float* __restrict__ s0,
                                        const float* __restrict__ s1,
                                        int row0, int stride, int k0, int t) {
  const int rr = t >> 3, cc = (t & 7) << 2;
#pragma unroll
  for (int p = 0; p < 64; p += 32) {
    const size_t off = (size_t)(row0 + rr + p) * stride + k0 + cc;
    float4 v = *reinterpret_cast<const float4*>(s0 + off);
    if (s1) {
      const float4 w = *reinterpret_cast<const float4*>(s1 + off);
      v.x += w.x; v.y += w.y; v.z += w.z; v.w += w.w;
    }
    dst[cc + 0][rr + p] = v.x; dst[cc + 1][rr + p] = v.y;
    dst[cc + 2][rr + p] = v.z; dst[cc + 3][rr + p] = v.w;
  }
}

// ---------------- Kernel 1: lower-triangular inverse (+ zero C) ----------------
// part1 = I - 0.5*A. Block bid<256: column bid of Ad = 2*inv(part1) - I -> P00,
// and zeroes its 512-float slice of C. Block 256: Bd -> U0 row 0; zero split parts.
__global__ __launch_bounds__(256) void k_inv(const float* __restrict__ A,
                                             const float* __restrict__ Bm,
                                             float* __restrict__ P00, float* P01,
                                             float* __restrict__ U0, float* U1,
                                             float* __restrict__ C) {
  const int bid = blockIdx.x;
  const int i = threadIdx.x;
  const int wave = i >> 6, lane = i & 63;
  __shared__ float xs[NORD];
  if (bid < NORD) {
    const int base = bid * 512;
    C[base + i] = 0.0f;
    C[base + 256 + i] = 0.0f;
  }
  float b = (bid < NORD) ? ((i == bid) ? 1.0f : 0.0f) : Bm[i];
  const float invd = 1.0f / (1.0f - 0.5f * A[i * NORD + i]);
  for (int w = 0; w < 4; ++w) {
    if (wave == w) {
      const int base = w << 6;
      for (int jj = 0; jj < 64; ++jj) {
        float bj = __shfl(b, jj);
        float dj = __shfl(invd, jj);
        float xj = bj * dj;
        if (lane > jj) {
          b += 0.5f * A[i * NORD + base + jj] * xj;
        } else if (lane == jj) {
          b = xj;
        }
      }
      xs[i] = b;
    }
    __syncthreads();
    if (wave > w) {
      const int base = w << 6;
      const float4* arow = reinterpret_cast<const float4*>(A + i * NORD + base);
#pragma unroll
      for (int q = 0; q < 16; ++q) {
        float4 a4 = arow[q];
        b += 0.5f * (a4.x * xs[base + 4 * q + 0] + a4.y * xs[base + 4 * q + 1] +
                     a4.z * xs[base + 4 * q + 2] + a4.w * xs[base + 4 * q + 3]);
      }
    }
  }
  if (bid < NORD) {
    P00[i * NORD + bid] = 2.0f * b - ((i == bid) ? 1.0f : 0.0f);
    if (P01) P01[(size_t)bid * 256 + i] = 0.0f;
  } else {
    U0[i] = b;
    if (U1) U1[i] = 0.0f;
  }
}

// ---------------- Kernel 2: one doubling round (verbatim from R6, proven) ----------------
// bid < n_apply: U[J+j] = P * U[j]   (64x64 tiles, split-K parts)
// else:          Pout   = P * P
__global__ __launch_bounds__(256) void k_stage(float* U0, float* U1,
                                               const float* Pin0, const float* Pin1,
                                               float* Pout0, float* Pout1,
                                               int J, int n_apply) {
  const int bid = blockIdx.x;
  const int t = threadIdx.x;
  const int tr = t >> 4, tc = t & 15;
  __shared__ float As[32][68];
  __shared__ float Bs[32][68];
  const int kspan = U1 ? 128 : 256;

  if (bid < n_apply) {
    int work = bid, ks = 0;
    if (U1) { ks = work & 1; work >>= 1; }
    const int j0 = (work >> 2) << 6;
    const int m0 = (work & 3) << 6;
    const int klo = ks * kspan;
    float acc[4][4] = {};
    for (int kc = 0; kc < kspan; kc += 32) {
      const int k0 = klo + kc;
      fill_tr(As, U0, U1, j0, NORD, k0, t);
      fill_tr(Bs, Pin0, Pin1, m0, NORD, k0, t);
      __syncthreads();
      tile_fma4(As, Bs, tr, tc, acc);
      __syncthreads();
    }
    float* Ud = ks ? U1 : U0;
#pragma unroll
    for (int ii = 0; ii < 4; ++ii) {
      const int lr = j0 + 4 * tr + ii;
      if (lr < J) {
        float4 v = {acc[ii][0], acc[ii][1], acc[ii][2], acc[ii][3]};
        *reinterpret_cast<float4*>(&Ud[(size_t)(J + lr) * NORD + m0 + 4 * tc]) = v;
      }
    }
  } else {
    int q = bid - n_apply, ks = 0;
    if (Pin1) { ks = q & 1; q >>= 1; }
    const int m0s = (q >> 2) << 6;
    const int n0 = (q & 3) << 6;
    const int klo = ks * kspan;
    const int rr = t >> 3, cc = (t & 7) << 2;
    float acc[4][4] = {};
    for (int kc = 0; kc < kspan; kc += 32) {
      const int k0 = klo + kc;
      fill_tr(As, Pin0, Pin1, m0s, NORD, k0, t);
#pragma unroll
      for (int p = 0; p < 64; p += 32) {
        const size_t off = (size_t)(k0 + rr) * NORD + n0 + cc + p;
        float4 v = *reinterpret_cast<const float4*>(Pin0 + off);
        if (Pin1) {
          const float4 w = *reinterpret_cast<const float4*>(Pin1 + off);
          v.x += w.x; v.y += w.y; v.z += w.z; v.w += w.w;
        }
        *reinterpret_cast<float4*>(&Bs[rr][cc + p]) = v;
      }
      __syncthreads();
      tile_fma4(As, Bs, tr, tc, acc);
      __syncthreads();
    }
    float* Pd = ks ? Pout1 : Pout0;
#pragma unroll
    for (int ii = 0; ii < 4; ++ii) {
      float4 v = {acc[ii][0], acc[ii][1], acc[ii][2], acc[ii][3]};
      *reinterpret_cast<float4*>(&Pd[(size_t)(m0s + 4 * tr + ii) * NORD + n0 + 4 * tc]) = v;
    }
  }
}

// ---------------- Kernel 3: C[b][m] += sum_k f[b][k] * Usum[4095-k][m] ----------------
// 16 row-tiles of 32 x 32 split-K (K=128 each) = 512 blocks (2/CU).
// Tile 32 x 256(full N), microtile 2x16 with cols 4tc+64j (2-way LDS = free).
__global__ __launch_bounds__(256) void k_final(const float* __restrict__ f,
                                               const float* __restrict__ U0,
                                               const float* U1,
                                               float* __restrict__ C) {
  const int bid = blockIdx.x;
  const int bt = bid >> 5;
  const int ks = bid & 31;
  const int b0 = bt << 5;
  const int t = threadIdx.x;
  const int tr = t >> 4, tc = t & 15;
  __shared__ float As[32][36];
  __shared__ float Bs[32][260];
  float acc[2][16] = {};
  for (int ch = 0; ch < 4; ++ch) {
    const int k0 = (ks << 7) + (ch << 5);
    {  // As[k][r] = f[b0+r][k0+k]  (coalesced: 8 lanes x float4 per row)
      const int rr = t >> 3, cc = (t & 7) << 2;
      const float4 v = *reinterpret_cast<const float4*>(
          f + (size_t)(b0 + rr) * TLEN + k0 + cc);
      As[cc + 0][rr] = v.x; As[cc + 1][rr] = v.y;
      As[cc + 2][rr] = v.z; As[cc + 3][rr] = v.w;
    }
    {  // Bs[k][m] = Usum[4095-(k0+k)][m]  (coalesced: 64 lanes x float4 per row)
      const int kk = t >> 6, c4 = (t & 63) << 2;
#pragma unroll
      for (int p = 0; p < 8; ++p) {
        const int row = (p << 2) + kk;
        const size_t off = (size_t)(TLEN - 1 - (k0 + row)) * NORD + c4;
        float4 v = *reinterpret_cast<const float4*>(U0 + off);
        if (U1) {
          const float4 w = *reinterpret_cast<const float4*>(U1 + off);
          v.x += w.x; v.y += w.y; v.z += w.z; v.w += w.w;
        }
        *reinterpret_cast<float4*>(&Bs[row][c4]) = v;
      }
    }
    __syncthreads();
#pragma unroll
    for (int k = 0; k < 32; ++k) {
      const float2 a2 = *reinterpret_cast<const float2*>(&As[k][2 * tr]);
#pragma unroll
      for (int j = 0; j < 4; ++j) {
        const float4 b4 = *reinterpret_cast<const float4*>(&Bs[k][(j << 6) + 4 * tc]);
        acc[0][4 * j + 0] += a2.x * b4.x; acc[0][4 * j + 1] += a2.x * b4.y;
        acc[0][4 * j + 2] += a2.x * b4.z; acc[0][4 * j + 3] += a2.x * b4.w;
        acc[1][4 * j + 0] += a2.y * b4.x; acc[1][4 * j + 1] += a2.y * b4.y;
        acc[1][4 * j + 2] += a2.y * b4.z; acc[1][4 * j + 3] += a2.y * b4.w;
      }
    }
    __syncthreads();
  }
#pragma unroll
  for (int i = 0; i < 2; ++i) {
    const size_t rowoff = (size_t)(b0 + 2 * tr + i) * NORD;
#pragma unroll
    for (int j = 0; j < 4; ++j)
#pragma unroll
      for (int q = 0; q < 4; ++q)
        atomicAdd(&C[rowoff + (j << 6) + 4 * tc + q], acc[i][4 * j + q]);
  }
}

// ---------------------------------------------------------------------------
extern "C" void kernel_launch(void* const* d_in, const int* in_sizes, int n_in,
                              void* d_out, int out_size, void* d_ws, size_t ws_size,
                              hipStream_t stream) {
  const float* f  = (const float*)d_in[0];   // (512, 4096)
  const float* A  = (const float*)d_in[1];   // (256, 256) lower triangular
  const float* Bm = (const float*)d_in[2];   // (256, 1)
  // d_in[3] = init_state == 0 -> no contribution.

  float* ws = (float*)d_ws;
  // KS=2: P00,P01,P10,P11 (4x65536) | U0,U1 (2x1048576)  = 9.44 MB
  const size_t need_split = (size_t)(4 * 65536 + 2 * 1048576) * sizeof(float);
  const int KS = (ws_size >= need_split) ? 2 : 1;

  float *P00, *P01, *P10, *P11, *U0, *U1;
  if (KS == 2) {
    P00 = ws;            P01 = ws + 65536;
    P10 = ws + 131072;   P11 = ws + 196608;
    U0  = ws + 262144;   U1  = ws + 1310720;
  } else {
    P00 = ws;            P01 = nullptr;
    P10 = ws + 65536;    P11 = nullptr;
    U0  = ws + 131072;   U1  = nullptr;
  }
  float* C = (float*)d_out;

  hipLaunchKernelGGL(k_inv, dim3(NORD + 1), dim3(256), 0, stream,
                     A, Bm, P00, P01, U0, U1, C);

  for (int s = 0; s <= 11; ++s) {
    const int J = 1 << s;
    const float* Pin0 = (s & 1) ? P10 : P00;
    const float* Pin1 = (s & 1) ? P11 : P01;
    float* Pout0 = (s & 1) ? P00 : P10;
    float* Pout1 = (s & 1) ? P01 : P11;
    const int rtiles = (J + 63) >> 6;
    const int n_apply = (rtiles << 2) * KS;
    const int n_sq = (s < 11) ? 16 * KS : 0;  // P^4096 unused
    hipLaunchKernelGGL(k_stage, dim3(n_apply + n_sq), dim3(256), 0, stream,
                       U0, U1, Pin0, Pin1, Pout0, Pout1, J, n_apply);
  }

  hipLaunchKernelGGL(k_final, dim3(512), dim3(256), 0, stream, f, U0, U1, C);
}